// Round 4
// baseline (600.682 us; speedup 1.0000x reference)
//
#include <hip/hip_runtime.h>

// VQ argmin: exact bit-level emulation of numpy fp32 reference:
//   A  = np.sum(flat*flat, axis=1)     (numpy pairwise-sum tree, fp32)
//   M2 = (2*flat) @ emb.T              (BLAS: sequential fp32 fma chain over d)
//   dist = (A - M2) + ee;  argmin_k (first-min ties)
// z_e_x: [B=16, D=256, H=64, W=64] fp32; embedding: [K=1024, D=256] fp32
// out: int32 [65536]
//
// R7: R3's hot loop restored byte-identical (single uniform kt_pass, KT=64,
// NKT=4, NSPLIT=4, launch_bounds(256,4) -- the proven 409us/no-spill point).
// A is computed in a straight-line PROLOGUE (exact a_kernel chain) before
// the kt loop: r[8] dies before acc[64] goes live, so peak pressure is
// unchanged; cost ~3-8us latency-hidden vs a_kernel's 45us wall pass.
// R6's mistake (A interleaved into kt=0's loop via it==0/8 branches) broke
// the z-prefetch pipeline: vq 409->472. Reverted.
// Combine via R3's proven pv/pk + combine_kernel (4 dispatches total,
// no memset/unpack).

#define D_DIM  256
#define K_DIM  1024
#define HW     4096
#define N_TOT  65536
#define NSPLIT 4
#define NKT    4
#define KT     64                 // acc regs per thread
#define KSPL   (K_DIM / NSPLIT)   // 256 k's per split = NKT*KT
#define F32MAX 3.402823466e38f

// ---- numpy pairwise_sum for ||e_k||^2 (n=256 = two 128-blocks of 8 accs)

__global__ void ee_kernel(const float* __restrict__ e, float* __restrict__ ee) {
#pragma clang fp contract(off)
    int k = blockIdx.x * blockDim.x + threadIdx.x;
    if (k >= K_DIM) return;
    const float* row = e + (size_t)k * D_DIM;
    float total = 0.0f;
    #pragma unroll
    for (int h = 0; h < 2; ++h) {
        const float* a = row + h * 128;
        float r[8];
        #pragma unroll
        for (int j = 0; j < 8; ++j) { float v = a[j]; r[j] = v * v; }
        #pragma unroll
        for (int i = 8; i < 128; i += 8) {
            #pragma unroll
            for (int j = 0; j < 8; ++j) { float v = a[i + j]; r[j] = r[j] + v * v; }
        }
        float s = ((r[0] + r[1]) + (r[2] + r[3])) + ((r[4] + r[5]) + (r[6] + r[7]));
        total = (h == 0) ? s : (total + s);
    }
    ee[k] = total;
}

// ---- transpose + fold the exact x2: eT[d][k] = 2*emb[k][d]
// LDS 32x32 tile, both global sides coalesced, +1 pad kills bank conflicts.

__global__ void et_kernel(const float* __restrict__ e, float* __restrict__ eT) {
    __shared__ float t[32][33];
    const int k0 = blockIdx.x * 32;
    const int d0 = blockIdx.y * 32;
    const int tx = threadIdx.x;         // 0..31
    const int ty = threadIdx.y;         // 0..7
    #pragma unroll
    for (int i = 0; i < 32; i += 8)
        t[ty + i][tx] = 2.0f * e[(size_t)(k0 + ty + i) * D_DIM + d0 + tx];
    __syncthreads();
    #pragma unroll
    for (int i = 0; i < 32; i += 8)
        eT[(size_t)(d0 + ty + i) * K_DIM + k0 + tx] = t[tx][ty + i];
}

// ---- one full-D pass over a KT-wide k tile (R3's exact uniform body):
// z VGPR ping-pong prefetch, eT rows wave-uniform -> SGPR broadcast operand.

__device__ __forceinline__ void kt_pass(const float* __restrict__ zp,
                                        const float* __restrict__ eT,
                                        int kbase,
                                        float (&za)[8], float (&zb)[8],
                                        float (&acc)[KT]) {
#pragma clang fp contract(off)
    #pragma unroll 1
    for (int it = 0; it < 16; ++it) {
        const int base = it * 16;
        // prefetch d = base+8 .. base+15
        #pragma unroll
        for (int i = 0; i < 8; ++i)
            zb[i] = zp[(size_t)((base + 8 + i) & (D_DIM - 1)) * HW];
        // compute d = base .. base+7 (ascending: exact fma chain)
        #pragma unroll
        for (int dd = 0; dd < 8; ++dd) {
            const float zv = za[dd];
            const float* __restrict__ er = eT + (size_t)(base + dd) * K_DIM + kbase;
            #pragma unroll
            for (int j = 0; j < KT; ++j)
                acc[j] = fmaf(zv, er[j], acc[j]);   // er[j] -> SGPR operand
        }
        // prefetch d = base+16 .. base+23; (mod 256) wrap at it=15 re-primes
        // za with d=0..7 for the next kt pass automatically.
        #pragma unroll
        for (int i = 0; i < 8; ++i)
            za[i] = zp[(size_t)((base + 16 + i) & (D_DIM - 1)) * HW];
        // compute d = base+8 .. base+15
        #pragma unroll
        for (int dd = 0; dd < 8; ++dd) {
            const float zv = zb[dd];
            const float* __restrict__ er = eT + (size_t)(base + 8 + dd) * K_DIM + kbase;
            #pragma unroll
            for (int j = 0; j < KT; ++j)
                acc[j] = fmaf(zv, er[j], acc[j]);
        }
    }
}

// ---- main: 1 n per thread, eT broadcast via SGPRs, 64-k acc tile, no LDS.
// R3-proven operating point: 4 blocks/CU, 4 waves/SIMD, 128-reg budget.

__launch_bounds__(256, 4)
__global__ void vq_partial(const float* __restrict__ z, const float* __restrict__ eT,
                           const float* __restrict__ ee,
                           float* __restrict__ pv, int* __restrict__ pk) {
#pragma clang fp contract(off)
    const int tid  = threadIdx.x;
    const int s    = blockIdx.x & (NSPLIT - 1);
    const int slab = blockIdx.x >> 2;
    const int n    = slab * 256 + tid;
    const int b    = n >> 12;
    const int hw   = n & (HW - 1);
    const float* __restrict__ zp = z + (size_t)b * D_DIM * HW + hw;
    const int kb0 = s * KSPL;

    // ---- A prologue: exact a_kernel pairwise tree. Straight-line, r[8]
    // dies before the kt loop's acc[64] goes live -> no pressure increase,
    // and the hot loop below is untouched (R6 lesson).
    float An;
    {
        float total = 0.0f;
        #pragma unroll
        for (int h = 0; h < 2; ++h) {
            float r[8];
            #pragma unroll
            for (int j = 0; j < 8; ++j) {
                float v = zp[(size_t)(h * 128 + j) * HW];
                r[j] = v * v;
            }
            #pragma unroll
            for (int i = 8; i < 128; i += 8) {
                #pragma unroll
                for (int j = 0; j < 8; ++j) {
                    float v = zp[(size_t)(h * 128 + i + j) * HW];
                    r[j] = r[j] + v * v;
                }
            }
            float sh = ((r[0] + r[1]) + (r[2] + r[3])) + ((r[4] + r[5]) + (r[6] + r[7]));
            total = (h == 0) ? sh : (total + sh);
        }
        An = total;
    }

    float bestv = F32MAX;
    int   bestk = 0;
    float za[8], zb[8];

    // prime za with d = 0..7
    #pragma unroll
    for (int i = 0; i < 8; ++i) za[i] = zp[(size_t)i * HW];

    #pragma unroll 1
    for (int kt = 0; kt < NKT; ++kt) {
        const int kbase = kb0 + kt * KT;
        float acc[KT];
        #pragma unroll
        for (int j = 0; j < KT; ++j) acc[j] = 0.0f;
        kt_pass(zp, eT, kbase, za, zb, acc);
        // epilogue: dist = (An - M2) + ee, k ascending -> first-min ties
        #pragma unroll
        for (int j = 0; j < KT; ++j) {
            const float dist = (An - acc[j]) + ee[kbase + j];
            if (dist < bestv) { bestv = dist; bestk = kbase + j; }
        }
    }

    pv[(size_t)s * N_TOT + n] = bestv;
    pk[(size_t)s * N_TOT + n] = bestk;
}

// ---- exact cross-split combine (splits ascending in k; strict < keeps lowest)

__global__ void combine_kernel(const float* __restrict__ pv, const int* __restrict__ pk,
                               int* __restrict__ out) {
    int n = blockIdx.x * blockDim.x + threadIdx.x;
    float bv = pv[n];
    int   bk = pk[n];
    #pragma unroll
    for (int s2 = 1; s2 < NSPLIT; ++s2) {
        float v = pv[(size_t)s2 * N_TOT + n];
        int   k = pk[(size_t)s2 * N_TOT + n];
        if (v < bv) { bv = v; bk = k; }
    }
    out[n] = bk;
}

extern "C" void kernel_launch(void* const* d_in, const int* in_sizes, int n_in,
                              void* d_out, int out_size, void* d_ws, size_t ws_size,
                              hipStream_t stream) {
    const float* z   = (const float*)d_in[0];   // [16,256,64,64]
    const float* emb = (const float*)d_in[1];   // [1024,256]
    int* out = (int*)d_out;                     // [65536] int32

    float* wsEE = (float*)d_ws;                     // 1024
    float* wsET = wsEE + K_DIM;                     // 262144
    float* wsPV = wsET + (size_t)D_DIM * K_DIM;     // 4*65536
    int*   wsPK = (int*)(wsPV + (size_t)NSPLIT * N_TOT);  // 4*65536

    et_kernel<<<dim3(K_DIM / 32, D_DIM / 32), dim3(32, 8), 0, stream>>>(emb, wsET);
    ee_kernel<<<K_DIM / 256, 256, 0, stream>>>(emb, wsEE);
    vq_partial<<<N_TOT / 256 * NSPLIT, 256, 0, stream>>>(z, wsET, wsEE, wsPV, wsPK);
    combine_kernel<<<N_TOT / 256, 256, 0, stream>>>(wsPV, wsPK, out);
}

// Round 5
// 498.824 us; speedup vs baseline: 1.2042x; 1.2042x over previous
//
#include <hip/hip_runtime.h>

// VQ argmin: exact bit-level emulation of numpy fp32 reference:
//   A  = np.sum(flat*flat, axis=1)     (numpy pairwise-sum tree, fp32)
//   M2 = (2*flat) @ emb.T              (BLAS: sequential fp32 fma chain over d)
//   dist = (A - M2) + ee;  argmin_k (first-min ties)
// z_e_x: [B=16, D=256, H=64, W=64] fp32; embedding: [K=1024, D=256] fp32
// out: int32 [65536]
//
// R8: SMEM-stall fix. R3's 31% stall = SGPR file too small to prefetch
// 64-wide eT rows (64 SGPRs/row, file ~102 -> ~1 row ahead vs ~2 needed at
// 250cy L2 latency). KT=32 + 2 n/thread: 32 SGPRs/row feed 64 FMAs -> ~3
// rows fit -> prefetch covers latency. Same FMA count/issue, same 128-reg
// (256,4) budget (acc 2x32=64, z 4-deep x 2 streams=16, 2nd z base is SGPR).
// NSPLIT=8, NKT=4, grid 1024 (4 blocks/CU proven point).
// A-fusion is permanently closed (R6 in-loop 472us, R7 prologue 558us vs
// separate 409+45): a_kernel separate, now 2 threads/n (independent 128-half
// trees, __shfl_xor combine, bitwise-exact) at 512 blocks -> ~2x faster.
// Combine: u64 lexicographic atomicMin (verified R4/R5/R6).

#define D_DIM  256
#define K_DIM  1024
#define HW     4096
#define N_TOT  65536
#define NSPLIT 8
#define NKT    4
#define KT     32                 // k's per acc tile (per n-stream)
#define KSPL   (K_DIM / NSPLIT)   // 128 = NKT*KT
#define NHALF  (N_TOT / 2)        // threads in vq grid handle 2 n each
#define F32MAX 3.402823466e38f

// ---- numpy pairwise_sum for ||e_k||^2 (n=256 = two 128-blocks of 8 accs)

__global__ void ee_kernel(const float* __restrict__ e, float* __restrict__ ee) {
#pragma clang fp contract(off)
    int k = blockIdx.x * blockDim.x + threadIdx.x;
    if (k >= K_DIM) return;
    const float* row = e + (size_t)k * D_DIM;
    float total = 0.0f;
    #pragma unroll
    for (int h = 0; h < 2; ++h) {
        const float* a = row + h * 128;
        float r[8];
        #pragma unroll
        for (int j = 0; j < 8; ++j) { float v = a[j]; r[j] = v * v; }
        #pragma unroll
        for (int i = 8; i < 128; i += 8) {
            #pragma unroll
            for (int j = 0; j < 8; ++j) { float v = a[i + j]; r[j] = r[j] + v * v; }
        }
        float s = ((r[0] + r[1]) + (r[2] + r[3])) + ((r[4] + r[5]) + (r[6] + r[7]));
        total = (h == 0) ? s : (total + s);
    }
    ee[k] = total;
}

// ---- A = numpy pairwise ||z_n||^2: 2 threads per n, one 128-half each
// (halves are independent 8-acc chains in the numpy tree; total = s0 + s1).
// Even lane holds h=0, odd h=1; __shfl_xor(1) pairs them. Bitwise-exact.

__global__ void a_kernel(const float* __restrict__ z, float* __restrict__ A) {
#pragma clang fp contract(off)
    int t = blockIdx.x * blockDim.x + threadIdx.x;   // 0 .. 2*N_TOT-1
    int n = t >> 1;
    int h = t & 1;
    int b  = n >> 12;
    int hw = n & (HW - 1);
    const float* base = z + (size_t)b * D_DIM * HW + hw + (size_t)(h * 128) * HW;
    float r[8];
    #pragma unroll
    for (int j = 0; j < 8; ++j) { float v = base[(size_t)j * HW]; r[j] = v * v; }
    #pragma unroll
    for (int i = 8; i < 128; i += 8) {
        #pragma unroll
        for (int j = 0; j < 8; ++j) {
            float v = base[(size_t)(i + j) * HW];
            r[j] = r[j] + v * v;
        }
    }
    float s = ((r[0] + r[1]) + (r[2] + r[3])) + ((r[4] + r[5]) + (r[6] + r[7]));
    float other = __shfl_xor(s, 1);
    if (h == 0) A[n] = s + other;    // total = s_half0 + s_half1 (exact order)
}

// ---- transpose + fold the exact x2: eT[d][k] = 2*emb[k][d]

__global__ void et_kernel(const float* __restrict__ e, float* __restrict__ eT) {
    __shared__ float t[32][33];
    const int k0 = blockIdx.x * 32;
    const int d0 = blockIdx.y * 32;
    const int tx = threadIdx.x;         // 0..31
    const int ty = threadIdx.y;         // 0..7
    #pragma unroll
    for (int i = 0; i < 32; i += 8)
        t[ty + i][tx] = 2.0f * e[(size_t)(k0 + ty + i) * D_DIM + d0 + tx];
    __syncthreads();
    #pragma unroll
    for (int i = 0; i < 32; i += 8)
        eT[(size_t)(d0 + ty + i) * K_DIM + k0 + tx] = t[tx][ty + i];
}

// ---- vq helpers: 4-deep z prefetch (both streams), 4-d compute group.
// All indices compile-time -> arrays stay in registers.

__device__ __forceinline__ void pf4(const float* __restrict__ zp0,
                                    const float* __restrict__ zp1,
                                    int df, float (&b0)[4], float (&b1)[4]) {
    #pragma unroll
    for (int i = 0; i < 4; ++i) {
        b0[i] = zp0[(size_t)((df + i) & (D_DIM - 1)) * HW];
        b1[i] = zp1[(size_t)((df + i) & (D_DIM - 1)) * HW];
    }
}

__device__ __forceinline__ void cp4(const float* __restrict__ eT, int dc, int kbase,
                                    const float (&b0)[4], const float (&b1)[4],
                                    float (&acc0)[KT], float (&acc1)[KT]) {
#pragma clang fp contract(off)
    #pragma unroll
    for (int dd = 0; dd < 4; ++dd) {
        // eT row is wave-uniform -> s_load; 32 SGPRs serve both streams
        const float* __restrict__ er = eT + (size_t)(dc + dd) * K_DIM + kbase;
        const float zv0 = b0[dd];
        const float zv1 = b1[dd];
        #pragma unroll
        for (int j = 0; j < KT; ++j) acc0[j] = fmaf(zv0, er[j], acc0[j]);
        #pragma unroll
        for (int j = 0; j < KT; ++j) acc1[j] = fmaf(zv1, er[j], acc1[j]);
    }
}

// one full-D pass over a KT-wide k tile, two n-streams.
// d ascending per stream: exact fp32 fma chain per (n,k).

__device__ __forceinline__ void kt_pass(const float* __restrict__ zp0,
                                        const float* __restrict__ zp1,
                                        const float* __restrict__ eT, int kbase,
                                        float (&za0)[4], float (&za1)[4],
                                        float (&zb0)[4], float (&zb1)[4],
                                        float (&acc0)[KT], float (&acc1)[KT]) {
#pragma clang fp contract(off)
    #pragma unroll 1
    for (int it = 0; it < 16; ++it) {
        const int base = it * 16;
        pf4(zp0, zp1, base + 4,  zb0, zb1);
        cp4(eT, base,      kbase, za0, za1, acc0, acc1);
        pf4(zp0, zp1, base + 8,  za0, za1);
        cp4(eT, base + 4,  kbase, zb0, zb1, acc0, acc1);
        pf4(zp0, zp1, base + 12, zb0, zb1);
        cp4(eT, base + 8,  kbase, za0, za1, acc0, acc1);
        pf4(zp0, zp1, base + 16, za0, za1);   // it=15 wraps -> re-primes d=0..3
        cp4(eT, base + 12, kbase, zb0, zb1, acc0, acc1);
    }
}

// ---- main: 2 n per thread (n, n+32768 -> b, b+8; same hw -> coalesced),
// eT broadcast via SGPRs (32/row, ~3 rows fit in SGPR file), no LDS.
// 4 blocks/CU, 4 waves/SIMD, 128-reg budget (proven no-spill point).

__launch_bounds__(256, 4)
__global__ void vq_partial(const float* __restrict__ z, const float* __restrict__ eT,
                           const float* __restrict__ A, const float* __restrict__ ee,
                           unsigned long long* __restrict__ packed) {
#pragma clang fp contract(off)
    const int tid  = threadIdx.x;
    const int s    = blockIdx.x & (NSPLIT - 1);   // co-resident blocks share s
    const int slab = blockIdx.x >> 3;
    const int n0   = slab * 256 + tid;            // 0 .. 32767
    const int n1   = n0 + NHALF;                  // b + 8, same hw
    const int b    = n0 >> 12;
    const int hw   = n0 & (HW - 1);
    const float* __restrict__ zp0 = z + (size_t)b * D_DIM * HW + hw;
    const float* __restrict__ zp1 = zp0 + (size_t)8 * D_DIM * HW;
    const int kb0 = s * KSPL;

    const float An0 = A[n0];
    const float An1 = A[n1];

    float bestv0 = F32MAX, bestv1 = F32MAX;
    int   bestk0 = 0,      bestk1 = 0;

    float za0[4], za1[4], zb0[4], zb1[4];
    pf4(zp0, zp1, 0, za0, za1);     // prime d = 0..3

    #pragma unroll 1
    for (int kt = 0; kt < NKT; ++kt) {
        const int kbase = kb0 + kt * KT;
        float acc0[KT], acc1[KT];
        #pragma unroll
        for (int j = 0; j < KT; ++j) { acc0[j] = 0.0f; acc1[j] = 0.0f; }

        kt_pass(zp0, zp1, eT, kbase, za0, za1, zb0, zb1, acc0, acc1);

        // epilogue: dist = (An - M2) + ee, k ascending -> first-min ties
        #pragma unroll
        for (int j = 0; j < KT; ++j) {
            const float ek = ee[kbase + j];
            const float d0 = (An0 - acc0[j]) + ek;
            const float d1 = (An1 - acc1[j]) + ek;
            if (d0 < bestv0) { bestv0 = d0; bestk0 = kbase + j; }
            if (d1 < bestv1) { bestv1 = d1; bestk1 = kbase + j; }
        }
    }

    // Order-preserving fp32 encode; lexicographic (dist, k) min across
    // splits. Equal dist bits -> lower k wins = first-min semantics.
    unsigned int vb0 = __float_as_uint(bestv0);
    vb0 = (vb0 & 0x80000000u) ? ~vb0 : (vb0 | 0x80000000u);
    atomicMin(&packed[n0], ((unsigned long long)vb0 << 32) | (unsigned int)bestk0);

    unsigned int vb1 = __float_as_uint(bestv1);
    vb1 = (vb1 & 0x80000000u) ? ~vb1 : (vb1 | 0x80000000u);
    atomicMin(&packed[n1], ((unsigned long long)vb1 << 32) | (unsigned int)bestk1);
}

__global__ void unpack_kernel(const unsigned long long* __restrict__ packed,
                              int* __restrict__ out) {
    int n = blockIdx.x * blockDim.x + threadIdx.x;
    out[n] = (int)(packed[n] & 0xFFFFFFFFull);
}

extern "C" void kernel_launch(void* const* d_in, const int* in_sizes, int n_in,
                              void* d_out, int out_size, void* d_ws, size_t ws_size,
                              hipStream_t stream) {
    const float* z   = (const float*)d_in[0];   // [16,256,64,64]
    const float* emb = (const float*)d_in[1];   // [1024,256]
    int* out = (int*)d_out;                     // [65536] int32

    float* wsEE = (float*)d_ws;                     // 1024
    float* wsA  = wsEE + K_DIM;                     // 65536
    float* wsET = wsA + N_TOT;                      // 262144
    unsigned long long* wsPacked =
        (unsigned long long*)(wsET + (size_t)D_DIM * K_DIM);  // 65536 u64

    hipMemsetAsync(wsPacked, 0xFF, (size_t)N_TOT * sizeof(unsigned long long),
                   stream);
    et_kernel<<<dim3(K_DIM / 32, D_DIM / 32), dim3(32, 8), 0, stream>>>(emb, wsET);
    ee_kernel<<<K_DIM / 256, 256, 0, stream>>>(emb, wsEE);
    a_kernel<<<2 * N_TOT / 256, 256, 0, stream>>>(z, wsA);
    vq_partial<<<NHALF / 256 * NSPLIT, 256, 0, stream>>>(z, wsET, wsA, wsEE,
                                                         wsPacked);
    unpack_kernel<<<N_TOT / 256, 256, 0, stream>>>(wsPacked, out);
}